// Round 4
// baseline (777.696 us; speedup 1.0000x reference)
//
#include <hip/hip_runtime.h>

#define T_LEN 512
#define D_DIM 32
#define N_DIM 64
#define B_ALL 128
#define R_TILE 8      // real batch rows per block (M=16 MFMA, rows permuted)
#define M_DIM 16      // MFMA M dimension
#define HSTR 72       // ushort row stride for sHh/sHl: 16B-aligned, bank-spread

typedef short s8v __attribute__((ext_vector_type(8)));   // 8 bf16 (4 VGPRs)
typedef float f4v __attribute__((ext_vector_type(4)));   // MFMA C/D
typedef float f2v __attribute__((ext_vector_type(2)));
typedef unsigned int uint;
typedef unsigned short u16;

__device__ __forceinline__ float rcp_f(float x) {
#if __has_builtin(__builtin_amdgcn_rcpf)
    return __builtin_amdgcn_rcpf(x);
#else
    return 1.0f / x;
#endif
}
__device__ __forceinline__ float tanh_f(float x) {
    float e = __expf(2.0f * x);
    return 1.0f - 2.0f * rcp_f(e + 1.0f);
}
__device__ __forceinline__ float sig_f(float x) {
    return rcp_f(1.0f + __expf(-x));
}
__device__ __forceinline__ uint f2bf(float f) {   // fp32 -> bf16 bits, RNE
    uint u = __float_as_uint(f);
    return (u + 0x7FFFu + ((u >> 16) & 1u)) >> 16;
}
__device__ __forceinline__ s8v pack4(uint a, uint b, uint c, uint d_) {
    union { uint u[4]; s8v v; } x;
    x.u[0] = a; x.u[1] = b; x.u[2] = c; x.u[3] = d_;
    return x.v;
}

// Grid 256 blocks (16 d-pairs x 16 row-octets) x 256 thr (4 waves) ->
// 1 block/CU, 1 wave/SIMD. Each block handles TWO d values: per wave, the
// d0 and d1 instruction streams are fully independent (own W-frags, own
// h-state, own LDS buffers), so the scheduler interleaves d1's MFMAs under
// d0's exp/rcp chains IN-WAVE -- guaranteed anti-phase, unlike R2's
// scheduler-dependent block de-phasing. Per-CU-step cost identical to R2
// (VALU 2x720, MFMA 192, LDS 32 b128) but barriers per d-step are HALVED
// (one barrier covers both d's step). x*U+b is folded into the MFMA C-in
// (acc preload), killing the acc zero-init movs and stage-3 adds.
// M-row permutation as R2: real row r at M index 4*(r>>1)+(r&1); lane
// (quad,col) owns rows 2quad,2quad+1 in C regs 0,1; regs 2,3 are zero rows.
__global__ void __launch_bounds__(256, 1)
imv_lstm_scan(const float* __restrict__ x,
              const float* __restrict__ Uj, const float* __restrict__ Ui,
              const float* __restrict__ Uf, const float* __restrict__ Uo,
              const float* __restrict__ Wj, const float* __restrict__ Wi,
              const float* __restrict__ Wf, const float* __restrict__ Wo,
              const float* __restrict__ bj, const float* __restrict__ bi_,
              const float* __restrict__ bf_, const float* __restrict__ bo,
              const float* __restrict__ Fa, const float* __restrict__ Fab,
              const float* __restrict__ Fbw, const float* __restrict__ Fbb,
              const float* __restrict__ Pw, const float* __restrict__ Pb,
              float* __restrict__ wmu, float* __restrict__ wbeta)
{
    __shared__ float sXT[2][T_LEN][R_TILE];   // 32 KB, [dd][t][r]
    __shared__ u16   sHh[2][2][M_DIM][HSTR];  // 9.2 KB, [dd][buf][Mrow][k]
    __shared__ u16   sHl[2][2][M_DIM][HSTR];  // 9.2 KB
    __shared__ float sPS[2][2][R_TILE][4];    // [dd][buf][row][wg]
    __shared__ float sPV[2][R_TILE][4];       // epilogue second buffer

    const int tid  = threadIdx.x;
    const int lane = tid & 63;
    const int wg   = tid >> 6;               // 0..3 (n-group)
    const int quad = lane >> 4;              // 0..3
    const int col  = lane & 15;
    const int d0   = (blockIdx.x & 15) * 2;  // d-pair base
    const int rt   = blockIdx.x >> 4;        // 0..15
    const int r0   = rt * R_TILE;
    const int n    = wg * 16 + col;          // this lane's n
    const int mrow = quad * 4;               // first M row of lane's 2 rows
    const int rrow = quad * 2;               // first real row of lane's 2

    // ---- stage x transposed for both d: sXT[dd][t][r] ----
    for (int i = tid; i < 2 * R_TILE * T_LEN; i += 256) {
        int dd = i >> 12, rem = i & 4095;
        int t = rem >> 3, r = rem & 7;
        sXT[dd][t][r] = x[((size_t)(r0 + r) * T_LEN + t) * D_DIM + d0 + dd];
    }
    // ---- h0 = 0 (both d, both buffers; zero M rows stay 0 forever) ----
    for (int i = tid; i < 2 * 2 * M_DIM * HSTR; i += 256) {
        ((u16*)sHh)[i] = 0; ((u16*)sHl)[i] = 0;
    }

    // ---- W fragments into registers: Bh/Bl[dd][gate][k-chunk] ----
    s8v Bh[2][4][2], Bl[2][4][2];
    #pragma unroll
    for (int dd = 0; dd < 2; ++dd) {
        #pragma unroll
        for (int g = 0; g < 4; ++g) {
            const float* Wg = (g == 0 ? Wj : g == 1 ? Wi : g == 2 ? Wf : Wo)
                              + (size_t)(d0 + dd) * (N_DIM * N_DIM);
            #pragma unroll
            for (int c = 0; c < 2; ++c) {
                uint hp[4], lp[4];
                #pragma unroll
                for (int jp = 0; jp < 4; ++jp) {
                    float w0 = Wg[(32 * c + quad * 8 + 2 * jp + 0) * N_DIM + n];
                    float w1 = Wg[(32 * c + quad * 8 + 2 * jp + 1) * N_DIM + n];
                    uint u0 = __float_as_uint(w0), u1 = __float_as_uint(w1);
                    uint h0b = u0 & 0xFFFF0000u, h1b = u1 & 0xFFFF0000u;
                    float l0 = w0 - __uint_as_float(h0b);
                    float l1 = w1 - __uint_as_float(h1b);
                    hp[jp] = (u0 >> 16) | h1b;
                    lp[jp] = f2bf(l0) | (f2bf(l1) << 16);
                }
                Bh[dd][g][c] = pack4(hp[0], hp[1], hp[2], hp[3]);
                Bl[dd][g][c] = pack4(lp[0], lp[1], lp[2], lp[3]);
            }
        }
    }

    // ---- per-(d,n) scalars ----
    float u_[2][4], cb_[2][4], fan_[2], fab_[2];
    #pragma unroll
    for (int dd = 0; dd < 2; ++dd) {
        const int dn = (d0 + dd) * N_DIM + n;
        u_[dd][0] = Uj[dn]; u_[dd][1] = Ui[dn];
        u_[dd][2] = Uf[dn]; u_[dd][3] = Uo[dn];
        cb_[dd][0] = bj[dn]; cb_[dd][1] = bi_[dn];
        cb_[dd][2] = bf_[dn]; cb_[dd][3] = bo[dn];
        fan_[dd] = Fa[dn];
        fab_[dd] = Fab[d0 + dd];
    }

    __syncthreads();

    float c_[2][2] = {{0.f,0.f},{0.f,0.f}};
    float h_[2][2] = {{0.f,0.f},{0.f,0.f}};
    float ga[2][2] = {{0.f,0.f},{0.f,0.f}};
    float as[2][2] = {{0.f,0.f},{0.f,0.f}};

    #pragma unroll 2
    for (int t = 0; t < T_LEN; ++t) {
        const int wb = t & 1;        // write buffer (h_t)
        const int rb = wb ^ 1;       // read buffer (h_{t-1})

        // ---- both d streams: read A, MFMA (C preloaded with x*U+b),
        //      stage3, h-write, partials. Streams independent -> the
        //      scheduler interleaves d1 MFMA under d0 trans chains. ----
        #pragma unroll
        for (int dd = 0; dd < 2; ++dd) {
            s8v Ah[2], Al[2];
            #pragma unroll
            for (int c = 0; c < 2; ++c) {
                Ah[c] = *(const s8v*)&sHh[dd][rb][col][32 * c + quad * 8];
                Al[c] = *(const s8v*)&sHl[dd][rb][col][32 * c + quad * 8];
            }

            f2v xr = *(const f2v*)&sXT[dd][t][rrow];
            f4v acc[4];
            #pragma unroll
            for (int g = 0; g < 4; ++g) {
                f4v a;
                a[0] = fmaf(xr[0], u_[dd][g], cb_[dd][g]);
                a[1] = fmaf(xr[1], u_[dd][g], cb_[dd][g]);
                a[2] = 0.f; a[3] = 0.f;
                #pragma unroll
                for (int c = 0; c < 2; ++c) {
                    a = __builtin_amdgcn_mfma_f32_16x16x32_bf16(Ah[c], Bh[dd][g][c], a, 0, 0, 0);
                    a = __builtin_amdgcn_mfma_f32_16x16x32_bf16(Al[c], Bh[dd][g][c], a, 0, 0, 0);
                    a = __builtin_amdgcn_mfma_f32_16x16x32_bf16(Ah[c], Bl[dd][g][c], a, 0, 0, 0);
                }
                acc[g] = a;
            }

            float ps[2];
            #pragma unroll
            for (int r = 0; r < 2; ++r) {
                float jp = acc[0][r];
                float ip = acc[1][r];
                float fp = acc[2][r];
                float op = acc[3][r];
                c_[dd][r] = fmaf(c_[dd][r], sig_f(fp), sig_f(ip) * tanh_f(jp));
                h_[dd][r] = sig_f(op) * tanh_f(c_[dd][r]);
                ps[r] = h_[dd][r] * fan_[dd];
            }
            #pragma unroll
            for (int r = 0; r < 2; ++r) {
                ps[r] += __shfl_xor(ps[r], 1);
                ps[r] += __shfl_xor(ps[r], 2);
                ps[r] += __shfl_xor(ps[r], 4);
                ps[r] += __shfl_xor(ps[r], 8);
            }

            #pragma unroll
            for (int r = 0; r < 2; ++r) {
                float hv = h_[dd][r];
                uint u = __float_as_uint(hv);
                uint hb = u & 0xFFFF0000u;
                float lo = hv - __uint_as_float(hb);
                sHh[dd][wb][mrow + r][n] = (u16)(u >> 16);
                sHl[dd][wb][mrow + r][n] = (u16)f2bf(lo);
            }
            if (col == 0) {
                sPS[dd][wb][rrow + 0][wg] = ps[0];
                sPS[dd][wb][rrow + 1][wg] = ps[1];
            }
        }

        __syncthreads();   // the ONLY barrier: h_t + partials for BOTH d

        #pragma unroll
        for (int dd = 0; dd < 2; ++dd) {
            #pragma unroll
            for (int r = 0; r < 2; ++r) {
                f4v tv = *(const f4v*)&sPS[dd][wb][rrow + r][0];
                float tot = tv[0] + tv[1] + tv[2] + tv[3];
                float al = __expf(tanh_f(tot + fab_[dd]));
                as[dd][r] += al;
                ga[dd][r] = fmaf(al, h_[dd][r], ga[dd][r]);
            }
        }
    }

    // ---- epilogue: mu, beta per (row, d) for both d ----
    const float pwa = Pw[n],  pwb = Pw[64 + n];
    const float fwa = Fbw[n], fwb = Fbw[64 + n];
    float pm[2][2], pv[2][2];
    #pragma unroll
    for (int dd = 0; dd < 2; ++dd) {
        #pragma unroll
        for (int r = 0; r < 2; ++r) {
            float gn = ga[dd][r] * rcp_f(as[dd][r]);
            pm[dd][r] = fmaf(gn, pwa, h_[dd][r] * pwb);
            pv[dd][r] = fmaf(gn, fwa, h_[dd][r] * fwb);
            pm[dd][r] += __shfl_xor(pm[dd][r], 1);
            pm[dd][r] += __shfl_xor(pm[dd][r], 2);
            pm[dd][r] += __shfl_xor(pm[dd][r], 4);
            pm[dd][r] += __shfl_xor(pm[dd][r], 8);
            pv[dd][r] += __shfl_xor(pv[dd][r], 1);
            pv[dd][r] += __shfl_xor(pv[dd][r], 2);
            pv[dd][r] += __shfl_xor(pv[dd][r], 4);
            pv[dd][r] += __shfl_xor(pv[dd][r], 8);
        }
    }
    __syncthreads();   // in-loop sPS reads done
    if (col == 0) {
        #pragma unroll
        for (int dd = 0; dd < 2; ++dd) {
            #pragma unroll
            for (int r = 0; r < 2; ++r) {
                sPS[dd][0][rrow + r][wg] = pm[dd][r];
                sPV[dd][rrow + r][wg]    = pv[dd][r];
            }
        }
    }
    __syncthreads();
    if (tid < R_TILE) {
        int r = tid;
        #pragma unroll
        for (int dd = 0; dd < 2; ++dd) {
            f4v a  = *(const f4v*)&sPS[dd][0][r][0];
            f4v b2 = *(const f4v*)&sPV[dd][r][0];
            float mu = a[0] + a[1] + a[2] + a[3] + Pb[0];
            float bt = __expf(tanh_f(b2[0] + b2[1] + b2[2] + b2[3] + Fbb[0]));
            wmu  [(r0 + r) * D_DIM + d0 + dd] = mu;
            wbeta[(r0 + r) * D_DIM + d0 + dd] = bt;
        }
    }
}

// beta softmax over d + weighted sum -> out[b]
__global__ void imv_finalize(const float* __restrict__ wmu,
                             const float* __restrict__ wbeta,
                             float* __restrict__ out)
{
    int b = blockIdx.x * 64 + threadIdx.x;
    if (b >= B_ALL) return;
    float s1 = 0.f, s2 = 0.f;
    for (int d = 0; d < D_DIM; ++d) {
        float be = wbeta[b * D_DIM + d];
        s1 = fmaf(be, wmu[b * D_DIM + d], s1);
        s2 += be;
    }
    out[b] = s1 / s2;
}

extern "C" void kernel_launch(void* const* d_in, const int* in_sizes, int n_in,
                              void* d_out, int out_size, void* d_ws, size_t ws_size,
                              hipStream_t stream)
{
    const float* x   = (const float*)d_in[0];
    const float* U_j = (const float*)d_in[1];
    const float* U_i = (const float*)d_in[2];
    const float* U_f = (const float*)d_in[3];
    const float* U_o = (const float*)d_in[4];
    const float* W_j = (const float*)d_in[5];
    const float* W_i = (const float*)d_in[6];
    const float* W_f = (const float*)d_in[7];
    const float* W_o = (const float*)d_in[8];
    const float* b_j = (const float*)d_in[9];
    const float* b_i = (const float*)d_in[10];
    const float* b_f = (const float*)d_in[11];
    const float* b_o = (const float*)d_in[12];
    const float* Fan  = (const float*)d_in[13];
    const float* Fanb = (const float*)d_in[14];
    const float* Fbw  = (const float*)d_in[15];
    const float* Fbb  = (const float*)d_in[16];
    const float* Phw  = (const float*)d_in[17];
    const float* Phb  = (const float*)d_in[18];

    float* wmu   = (float*)d_ws;
    float* wbeta = wmu + B_ALL * D_DIM;

    imv_lstm_scan<<<dim3(256), dim3(256), 0, stream>>>(
        x, U_j, U_i, U_f, U_o, W_j, W_i, W_f, W_o,
        b_j, b_i, b_f, b_o, Fan, Fanb, Fbw, Fbb, Phw, Phb,
        wmu, wbeta);

    imv_finalize<<<dim3(2), dim3(64), 0, stream>>>(wmu, wbeta, (float*)d_out);
}

// Round 5
// 602.452 us; speedup vs baseline: 1.2909x; 1.2909x over previous
//
#include <hip/hip_runtime.h>

#define T_LEN 512
#define D_DIM 32
#define N_DIM 64
#define B_ALL 128
#define R_TILE 8      // real batch rows per block (M=16 MFMA, rows permuted)
#define M_DIM 16      // MFMA M dimension
#define HSTR 72       // ushort row stride for sHh/sHl: 16B-aligned, bank-spread

typedef short s8v __attribute__((ext_vector_type(8)));   // 8 bf16 (4 VGPRs)
typedef float f4v __attribute__((ext_vector_type(4)));   // MFMA C/D
typedef float f2v __attribute__((ext_vector_type(2)));
typedef unsigned int uint;
typedef unsigned short u16;

__device__ __forceinline__ float rcp_f(float x) {
#if __has_builtin(__builtin_amdgcn_rcpf)
    return __builtin_amdgcn_rcpf(x);
#else
    return 1.0f / x;
#endif
}
__device__ __forceinline__ float tanh_f(float x) {
    float e = __expf(2.0f * x);
    return 1.0f - 2.0f * rcp_f(e + 1.0f);
}
__device__ __forceinline__ float sig_f(float x) {
    return rcp_f(1.0f + __expf(-x));
}
__device__ __forceinline__ uint f2bf(float f) {   // fp32 -> bf16 bits, RNE
    uint u = __float_as_uint(f);
    return (u + 0x7FFFu + ((u >> 16) & 1u)) >> 16;
}
__device__ __forceinline__ s8v pack4(uint a, uint b, uint c, uint d_) {
    union { uint u[4]; s8v v; } x;
    x.u[0] = a; x.u[1] = b; x.u[2] = c; x.u[3] = d_;
    return x.v;
}

// R2 structure (best: 540us): grid 512 blocks (32 d x 16 row-octets) x
// 256 thr (4 waves) -> 2 independent blocks/CU, 2 de-phased waves/SIMD.
// R5 delta: SHORTEN the barrier-to-barrier critical path.
//  (a) alpha pipeline deferred one step: step t shfl-reduces step t-1's
//      ps partials (independent of t's h-chain -> fills stall gaps) and
//      consumes alpha(t-1) after the barrier, where it overlaps t+1's
//      MFMA region. The 4-deep serial shfl chain and the sPS-read+tanh+exp
//      tail leave the critical path.
//  (b) x*U+b folded into MFMA C-in (kills acc zero-init + stage-3 adds;
//      verified harmless in R4).
// Critical path/step is now: A-read -> MFMA chain -> gate trans -> h-write
// -> barrier. M-row permutation as R2: real row r at M index 4*(r>>1)+(r&1);
// lane (quad,col) owns rows 2quad,2quad+1 in C regs 0,1; regs 2,3 zero.
__global__ void __launch_bounds__(256, 2)
imv_lstm_scan(const float* __restrict__ x,
              const float* __restrict__ Uj, const float* __restrict__ Ui,
              const float* __restrict__ Uf, const float* __restrict__ Uo,
              const float* __restrict__ Wj, const float* __restrict__ Wi,
              const float* __restrict__ Wf, const float* __restrict__ Wo,
              const float* __restrict__ bj, const float* __restrict__ bi_,
              const float* __restrict__ bf_, const float* __restrict__ bo,
              const float* __restrict__ Fa, const float* __restrict__ Fab,
              const float* __restrict__ Fbw, const float* __restrict__ Fbb,
              const float* __restrict__ Pw, const float* __restrict__ Pb,
              float* __restrict__ wmu, float* __restrict__ wbeta)
{
    __shared__ float sXT[T_LEN][R_TILE];     // 16 KB, [t][r]
    __shared__ u16   sHh[2][M_DIM][HSTR];    // 4.5 KB, h hi bf16, [buf][Mrow][k]
    __shared__ u16   sHl[2][M_DIM][HSTR];    // 4.5 KB, h lo bf16
    __shared__ float sPS[2][R_TILE][4];      // alpha partials [buf][row][wg]
    __shared__ float sPV[R_TILE][4];         // epilogue second buffer

    const int tid  = threadIdx.x;
    const int lane = tid & 63;
    const int wg   = tid >> 6;               // 0..3 (n-group)
    const int quad = lane >> 4;              // 0..3
    const int col  = lane & 15;
    const int d    = blockIdx.x & 31;
    const int rt   = blockIdx.x >> 5;        // 0..15
    const int r0   = rt * R_TILE;
    const int n    = wg * 16 + col;          // this lane's n
    const int mrow = quad * 4;               // first M row of lane's 2 rows
    const int rrow = quad * 2;               // first real row of lane's 2

    // ---- stage x transposed: sXT[t][r] ----
    for (int i = tid; i < R_TILE * T_LEN; i += 256) {
        int t = i >> 3, r = i & 7;
        sXT[t][r] = x[((size_t)(r0 + r) * T_LEN + t) * D_DIM + d];
    }
    // ---- h0 = 0 (zero both buffers; unwritten M rows stay 0 forever) ----
    for (int i = tid; i < 2 * M_DIM * HSTR; i += 256) {
        ((u16*)sHh)[i] = 0; ((u16*)sHl)[i] = 0;
    }

    // ---- W fragments into registers: Bh/Bl[gate][k-chunk] ----
    s8v Bh[4][2], Bl[4][2];
    #pragma unroll
    for (int g = 0; g < 4; ++g) {
        const float* Wg = (g == 0 ? Wj : g == 1 ? Wi : g == 2 ? Wf : Wo)
                          + d * (N_DIM * N_DIM);
        #pragma unroll
        for (int c = 0; c < 2; ++c) {
            uint hp[4], lp[4];
            #pragma unroll
            for (int jp = 0; jp < 4; ++jp) {
                float w0 = Wg[(32 * c + quad * 8 + 2 * jp + 0) * N_DIM + n];
                float w1 = Wg[(32 * c + quad * 8 + 2 * jp + 1) * N_DIM + n];
                uint u0 = __float_as_uint(w0), u1 = __float_as_uint(w1);
                uint h0b = u0 & 0xFFFF0000u, h1b = u1 & 0xFFFF0000u;
                float l0 = w0 - __uint_as_float(h0b);
                float l1 = w1 - __uint_as_float(h1b);
                hp[jp] = (u0 >> 16) | h1b;
                lp[jp] = f2bf(l0) | (f2bf(l1) << 16);
            }
            Bh[g][c] = pack4(hp[0], hp[1], hp[2], hp[3]);
            Bl[g][c] = pack4(lp[0], lp[1], lp[2], lp[3]);
        }
    }

    const int dn = d * N_DIM + n;
    const float u_j = Uj[dn], u_i = Ui[dn], u_f = Uf[dn], u_o = Uo[dn];
    const float cbj = bj[dn], cbi = bi_[dn], cbf = bf_[dn], cbo = bo[dn];
    const float fan = Fa[dn];
    const float fab = Fab[d];

    __syncthreads();

    float c_[2]   = {0.f, 0.f};
    float h_p[2]  = {0.f, 0.f};   // h of previous step (alpha pipeline)
    float ps_p[2] = {0.f, 0.f};   // unreduced partials of previous step
    float ga[2]   = {0.f, 0.f};
    float as[2]   = {0.f, 0.f};

    #pragma unroll 2
    for (int t = 0; t < T_LEN; ++t) {
        const int wb = t & 1;        // write buffer (h_t)
        const int rb = wb ^ 1;       // read buffer (h_{t-1})

        // ---- A fragments: direct b128 reads, zero unpack ----
        s8v Ah[2], Al[2];
        #pragma unroll
        for (int c = 0; c < 2; ++c) {
            Ah[c] = *(const s8v*)&sHh[rb][col][32 * c + quad * 8];
            Al[c] = *(const s8v*)&sHl[rb][col][32 * c + quad * 8];
        }

        // ---- 24 MFMAs, C preloaded with x*U+b for the 2 real rows ----
        f2v xr = *(const f2v*)&sXT[t][rrow];
        f4v acc[4];
        #pragma unroll
        for (int g = 0; g < 4; ++g) {
            const float ug = (g == 0 ? u_j : g == 1 ? u_i : g == 2 ? u_f : u_o);
            const float cg = (g == 0 ? cbj : g == 1 ? cbi : g == 2 ? cbf : cbo);
            f4v a;
            a[0] = fmaf(xr[0], ug, cg);
            a[1] = fmaf(xr[1], ug, cg);
            a[2] = 0.f; a[3] = 0.f;
            #pragma unroll
            for (int c = 0; c < 2; ++c) {
                a = __builtin_amdgcn_mfma_f32_16x16x32_bf16(Ah[c], Bh[g][c], a, 0, 0, 0);
                a = __builtin_amdgcn_mfma_f32_16x16x32_bf16(Al[c], Bh[g][c], a, 0, 0, 0);
                a = __builtin_amdgcn_mfma_f32_16x16x32_bf16(Ah[c], Bl[g][c], a, 0, 0, 0);
            }
            acc[g] = a;
        }

        // ---- gates for this lane's 2 rows ----
        float hn[2], psn[2];
        #pragma unroll
        for (int r = 0; r < 2; ++r) {
            float jp = acc[0][r];
            float ip = acc[1][r];
            float fp = acc[2][r];
            float op = acc[3][r];
            c_[r] = fmaf(c_[r], sig_f(fp), sig_f(ip) * tanh_f(jp));
            hn[r] = sig_f(op) * tanh_f(c_[r]);
            psn[r] = hn[r] * fan;
        }

        // ---- write h_t (hi/lo planes, M rows mrow..mrow+1) ----
        #pragma unroll
        for (int r = 0; r < 2; ++r) {
            float hv = hn[r];
            uint u = __float_as_uint(hv);
            uint hb = u & 0xFFFF0000u;
            float lo = hv - __uint_as_float(hb);
            sHh[wb][mrow + r][n] = (u16)(u >> 16);
            sHl[wb][mrow + r][n] = (u16)f2bf(lo);
        }

        // ---- PREVIOUS step's partial reduce (independent of this step's
        //      chain: scheduler fills MFMA/trans stall gaps with it) ----
        float pp[2] = {ps_p[0], ps_p[1]};
        #pragma unroll
        for (int r = 0; r < 2; ++r) {
            pp[r] += __shfl_xor(pp[r], 1);
            pp[r] += __shfl_xor(pp[r], 2);
            pp[r] += __shfl_xor(pp[r], 4);
            pp[r] += __shfl_xor(pp[r], 8);
        }
        if (col == 0) {
            sPS[wb][rrow + 0][wg] = pp[0];
            sPS[wb][rrow + 1][wg] = pp[1];
        }

        __syncthreads();   // the ONLY barrier: h_t + partials(t-1) visible

        // ---- alpha(t-1): post-barrier, overlaps next step's MFMA ----
        if (t > 0) {
            #pragma unroll
            for (int r = 0; r < 2; ++r) {
                f4v tv = *(const f4v*)&sPS[wb][rrow + r][0];
                float tot = tv[0] + tv[1] + tv[2] + tv[3];
                float al = __expf(tanh_f(tot + fab));
                as[r] += al;
                ga[r] = fmaf(al, h_p[r], ga[r]);
            }
        }
        h_p[0] = hn[0];  h_p[1] = hn[1];
        ps_p[0] = psn[0]; ps_p[1] = psn[1];
    }

    // ---- drain the alpha pipeline: final step t = T_LEN-1 ----
    {
        float pp[2] = {ps_p[0], ps_p[1]};
        #pragma unroll
        for (int r = 0; r < 2; ++r) {
            pp[r] += __shfl_xor(pp[r], 1);
            pp[r] += __shfl_xor(pp[r], 2);
            pp[r] += __shfl_xor(pp[r], 4);
            pp[r] += __shfl_xor(pp[r], 8);
        }
        __syncthreads();   // all in-loop sPS reads done
        if (col == 0) {
            sPS[0][rrow + 0][wg] = pp[0];
            sPS[0][rrow + 1][wg] = pp[1];
        }
        __syncthreads();
        #pragma unroll
        for (int r = 0; r < 2; ++r) {
            f4v tv = *(const f4v*)&sPS[0][rrow + r][0];
            float tot = tv[0] + tv[1] + tv[2] + tv[3];
            float al = __expf(tanh_f(tot + fab));
            as[r] += al;
            ga[r] = fmaf(al, h_p[r], ga[r]);
        }
    }

    // ---- epilogue: mu, beta per (row, d); h_p holds h_T ----
    const float pwa = Pw[n],  pwb = Pw[64 + n];
    const float fwa = Fbw[n], fwb = Fbw[64 + n];
    float pm[2], pv[2];
    #pragma unroll
    for (int r = 0; r < 2; ++r) {
        float gn = ga[r] * rcp_f(as[r]);
        pm[r] = fmaf(gn, pwa, h_p[r] * pwb);
        pv[r] = fmaf(gn, fwa, h_p[r] * fwb);
        pm[r] += __shfl_xor(pm[r], 1); pm[r] += __shfl_xor(pm[r], 2);
        pm[r] += __shfl_xor(pm[r], 4); pm[r] += __shfl_xor(pm[r], 8);
        pv[r] += __shfl_xor(pv[r], 1); pv[r] += __shfl_xor(pv[r], 2);
        pv[r] += __shfl_xor(pv[r], 4); pv[r] += __shfl_xor(pv[r], 8);
    }
    __syncthreads();   // drain-phase sPS reads done
    if (col == 0) {
        #pragma unroll
        for (int r = 0; r < 2; ++r) {
            sPS[0][rrow + r][wg] = pm[r];
            sPV[rrow + r][wg]    = pv[r];
        }
    }
    __syncthreads();
    if (tid < R_TILE) {
        int r = tid;
        f4v a  = *(const f4v*)&sPS[0][r][0];
        f4v b2 = *(const f4v*)&sPV[r][0];
        float mu = a[0] + a[1] + a[2] + a[3] + Pb[0];
        float bt = __expf(tanh_f(b2[0] + b2[1] + b2[2] + b2[3] + Fbb[0]));
        wmu  [(r0 + r) * D_DIM + d] = mu;
        wbeta[(r0 + r) * D_DIM + d] = bt;
    }
}

// beta softmax over d + weighted sum -> out[b]
__global__ void imv_finalize(const float* __restrict__ wmu,
                             const float* __restrict__ wbeta,
                             float* __restrict__ out)
{
    int b = blockIdx.x * 64 + threadIdx.x;
    if (b >= B_ALL) return;
    float s1 = 0.f, s2 = 0.f;
    for (int d = 0; d < D_DIM; ++d) {
        float be = wbeta[b * D_DIM + d];
        s1 = fmaf(be, wmu[b * D_DIM + d], s1);
        s2 += be;
    }
    out[b] = s1 / s2;
}

extern "C" void kernel_launch(void* const* d_in, const int* in_sizes, int n_in,
                              void* d_out, int out_size, void* d_ws, size_t ws_size,
                              hipStream_t stream)
{
    const float* x   = (const float*)d_in[0];
    const float* U_j = (const float*)d_in[1];
    const float* U_i = (const float*)d_in[2];
    const float* U_f = (const float*)d_in[3];
    const float* U_o = (const float*)d_in[4];
    const float* W_j = (const float*)d_in[5];
    const float* W_i = (const float*)d_in[6];
    const float* W_f = (const float*)d_in[7];
    const float* W_o = (const float*)d_in[8];
    const float* b_j = (const float*)d_in[9];
    const float* b_i = (const float*)d_in[10];
    const float* b_f = (const float*)d_in[11];
    const float* b_o = (const float*)d_in[12];
    const float* Fan  = (const float*)d_in[13];
    const float* Fanb = (const float*)d_in[14];
    const float* Fbw  = (const float*)d_in[15];
    const float* Fbb  = (const float*)d_in[16];
    const float* Phw  = (const float*)d_in[17];
    const float* Phb  = (const float*)d_in[18];

    float* wmu   = (float*)d_ws;
    float* wbeta = wmu + B_ALL * D_DIM;

    imv_lstm_scan<<<dim3(512), dim3(256), 0, stream>>>(
        x, U_j, U_i, U_f, U_o, W_j, W_i, W_f, W_o,
        b_j, b_i, b_f, b_o, Fan, Fanb, Fbw, Fbb, Phw, Phb,
        wmu, wbeta);

    imv_finalize<<<dim3(2), dim3(64), 0, stream>>>(wmu, wbeta, (float*)d_out);
}

// Round 6
// 601.287 us; speedup vs baseline: 1.2934x; 1.0019x over previous
//
#include <hip/hip_runtime.h>

#define T_LEN 512
#define D_DIM 32
#define N_DIM 64
#define B_ALL 128
#define R_TILE 8      // real batch rows per block (M=16 MFMA, rows permuted)
#define M_DIM 16      // MFMA M dimension
#define HSTR 72       // ushort row stride for sHh/sHl: 16B-aligned, bank-spread

typedef short s8v __attribute__((ext_vector_type(8)));   // 8 bf16 (4 VGPRs)
typedef float f4v __attribute__((ext_vector_type(4)));   // MFMA C/D
typedef float f2v __attribute__((ext_vector_type(2)));
typedef unsigned int uint;
typedef unsigned short u16;

__device__ __forceinline__ float rcp_f(float x) {
#if __has_builtin(__builtin_amdgcn_rcpf)
    return __builtin_amdgcn_rcpf(x);
#else
    return 1.0f / x;
#endif
}
__device__ __forceinline__ float tanh_f(float x) {
    float e = __expf(2.0f * x);
    return 1.0f - 2.0f * rcp_f(e + 1.0f);
}
__device__ __forceinline__ float sig_f(float x) {
    return rcp_f(1.0f + __expf(-x));
}
__device__ __forceinline__ uint f2bf(float f) {   // fp32 -> bf16 bits, RNE
    uint u = __float_as_uint(f);
    return (u + 0x7FFFu + ((u >> 16) & 1u)) >> 16;
}
__device__ __forceinline__ s8v pack4(uint a, uint b, uint c, uint d_) {
    union { uint u[4]; s8v v; } x;
    x.u[0] = a; x.u[1] = b; x.u[2] = c; x.u[3] = d_;
    return x.v;
}

// R2 structure (best: 540us): grid 512 blocks (32 d x 16 row-octets) x
// 256 thr (4 waves) -> 2 independent blocks/CU, 2 de-phased waves/SIMD.
// R6 delta (one unit): SPLIT ACCUMULATORS. R2 chained 6 MFMAs per gate on
// one accumulator (2 K-chunks x 3 hi/lo terms) -> 6-deep dependency chain;
// with only 4 chains/wave and anti-phased co-blocks, the matrix pipe could
// not hide its own dep latency (needs ~8 chains at ~40cy lat / 5cy issue).
// Now K-chunk 0 -> a0, K-chunk 1 -> a1 (two independent 3-deep chains per
// gate = 8 chains/wave), merged by one f32 add. Rider: a0 regs 0-1
// preloaded with x*U+b (C-in fold, proven bitwise-harmless in R4/R5).
// Alpha reduce is R2-style: same-step, pre-barrier. Everything else
// byte-identical to R2. M-row permutation: real row r at M index
// 4*(r>>1)+(r&1); lane (quad,col) owns rows 2quad,2quad+1 in C regs 0,1.
__global__ void __launch_bounds__(256, 2)
imv_lstm_scan(const float* __restrict__ x,
              const float* __restrict__ Uj, const float* __restrict__ Ui,
              const float* __restrict__ Uf, const float* __restrict__ Uo,
              const float* __restrict__ Wj, const float* __restrict__ Wi,
              const float* __restrict__ Wf, const float* __restrict__ Wo,
              const float* __restrict__ bj, const float* __restrict__ bi_,
              const float* __restrict__ bf_, const float* __restrict__ bo,
              const float* __restrict__ Fa, const float* __restrict__ Fab,
              const float* __restrict__ Fbw, const float* __restrict__ Fbb,
              const float* __restrict__ Pw, const float* __restrict__ Pb,
              float* __restrict__ wmu, float* __restrict__ wbeta)
{
    __shared__ float sXT[T_LEN][R_TILE];     // 16 KB, [t][r]
    __shared__ u16   sHh[2][M_DIM][HSTR];    // 4.5 KB, h hi bf16, [buf][Mrow][k]
    __shared__ u16   sHl[2][M_DIM][HSTR];    // 4.5 KB, h lo bf16
    __shared__ float sPS[2][R_TILE][4];      // alpha partials [buf][row][wg]
    __shared__ float sPV[R_TILE][4];         // epilogue second buffer

    const int tid  = threadIdx.x;
    const int lane = tid & 63;
    const int wg   = tid >> 6;               // 0..3 (n-group)
    const int quad = lane >> 4;              // 0..3
    const int col  = lane & 15;
    const int d    = blockIdx.x & 31;
    const int rt   = blockIdx.x >> 5;        // 0..15
    const int r0   = rt * R_TILE;
    const int n    = wg * 16 + col;          // this lane's n
    const int mrow = quad * 4;               // first M row of lane's 2 rows
    const int rrow = quad * 2;               // first real row of lane's 2

    // ---- stage x transposed: sXT[t][r] ----
    for (int i = tid; i < R_TILE * T_LEN; i += 256) {
        int t = i >> 3, r = i & 7;
        sXT[t][r] = x[((size_t)(r0 + r) * T_LEN + t) * D_DIM + d];
    }
    // ---- h0 = 0 (zero both buffers; unwritten M rows stay 0 forever) ----
    for (int i = tid; i < 2 * M_DIM * HSTR; i += 256) {
        ((u16*)sHh)[i] = 0; ((u16*)sHl)[i] = 0;
    }

    // ---- W fragments into registers: Bh/Bl[gate][k-chunk] ----
    s8v Bh[4][2], Bl[4][2];
    #pragma unroll
    for (int g = 0; g < 4; ++g) {
        const float* Wg = (g == 0 ? Wj : g == 1 ? Wi : g == 2 ? Wf : Wo)
                          + d * (N_DIM * N_DIM);
        #pragma unroll
        for (int c = 0; c < 2; ++c) {
            uint hp[4], lp[4];
            #pragma unroll
            for (int jp = 0; jp < 4; ++jp) {
                float w0 = Wg[(32 * c + quad * 8 + 2 * jp + 0) * N_DIM + n];
                float w1 = Wg[(32 * c + quad * 8 + 2 * jp + 1) * N_DIM + n];
                uint u0 = __float_as_uint(w0), u1 = __float_as_uint(w1);
                uint h0b = u0 & 0xFFFF0000u, h1b = u1 & 0xFFFF0000u;
                float l0 = w0 - __uint_as_float(h0b);
                float l1 = w1 - __uint_as_float(h1b);
                hp[jp] = (u0 >> 16) | h1b;
                lp[jp] = f2bf(l0) | (f2bf(l1) << 16);
            }
            Bh[g][c] = pack4(hp[0], hp[1], hp[2], hp[3]);
            Bl[g][c] = pack4(lp[0], lp[1], lp[2], lp[3]);
        }
    }

    const int dn = d * N_DIM + n;
    const float u_j = Uj[dn], u_i = Ui[dn], u_f = Uf[dn], u_o = Uo[dn];
    const float cbj = bj[dn], cbi = bi_[dn], cbf = bf_[dn], cbo = bo[dn];
    const float fan = Fa[dn];
    const float fab = Fab[d];

    __syncthreads();

    float c_[2] = {0.f, 0.f};
    float h_[2] = {0.f, 0.f};
    float ga[2] = {0.f, 0.f};
    float as[2] = {0.f, 0.f};

    #pragma unroll 2
    for (int t = 0; t < T_LEN; ++t) {
        const int wb = t & 1;        // write buffer (h_t)
        const int rb = wb ^ 1;       // read buffer (h_{t-1})

        // ---- A fragments: direct b128 reads, zero unpack ----
        s8v Ah[2], Al[2];
        #pragma unroll
        for (int c = 0; c < 2; ++c) {
            Ah[c] = *(const s8v*)&sHh[rb][col][32 * c + quad * 8];
            Al[c] = *(const s8v*)&sHl[rb][col][32 * c + quad * 8];
        }

        // ---- 24 MFMAs: 4 gates x 2 independent 3-chains (split acc) ----
        f2v xr = *(const f2v*)&sXT[t][rrow];
        f4v acc[4];
        #pragma unroll
        for (int g = 0; g < 4; ++g) {
            const float ug = (g == 0 ? u_j : g == 1 ? u_i : g == 2 ? u_f : u_o);
            const float cg = (g == 0 ? cbj : g == 1 ? cbi : g == 2 ? cbf : cbo);
            f4v a0, a1;
            a0[0] = fmaf(xr[0], ug, cg);
            a0[1] = fmaf(xr[1], ug, cg);
            a0[2] = 0.f; a0[3] = 0.f;
            a1[0] = 0.f; a1[1] = 0.f; a1[2] = 0.f; a1[3] = 0.f;
            // chain 0: K-chunk 0 (3-deep)
            a0 = __builtin_amdgcn_mfma_f32_16x16x32_bf16(Ah[0], Bh[g][0], a0, 0, 0, 0);
            a0 = __builtin_amdgcn_mfma_f32_16x16x32_bf16(Al[0], Bh[g][0], a0, 0, 0, 0);
            a0 = __builtin_amdgcn_mfma_f32_16x16x32_bf16(Ah[0], Bl[g][0], a0, 0, 0, 0);
            // chain 1: K-chunk 1 (3-deep, independent of chain 0)
            a1 = __builtin_amdgcn_mfma_f32_16x16x32_bf16(Ah[1], Bh[g][1], a1, 0, 0, 0);
            a1 = __builtin_amdgcn_mfma_f32_16x16x32_bf16(Al[1], Bh[g][1], a1, 0, 0, 0);
            a1 = __builtin_amdgcn_mfma_f32_16x16x32_bf16(Ah[1], Bl[g][1], a1, 0, 0, 0);
            acc[g] = a0 + a1;   // merge (only regs 0,1 consumed downstream)
        }

        // ---- stage 3: C regs 0,1 = real rows rrow, rrow+1 at n ----
        float ps[2];
        #pragma unroll
        for (int r = 0; r < 2; ++r) {
            float jp = acc[0][r];
            float ip = acc[1][r];
            float fp = acc[2][r];
            float op = acc[3][r];
            c_[r] = fmaf(c_[r], sig_f(fp), sig_f(ip) * tanh_f(jp));
            h_[r] = sig_f(op) * tanh_f(c_[r]);
            ps[r] = h_[r] * fan;
        }
        // reduce ps over this wave's 16 n (stays within quad-group)
        #pragma unroll
        for (int r = 0; r < 2; ++r) {
            ps[r] += __shfl_xor(ps[r], 1);
            ps[r] += __shfl_xor(ps[r], 2);
            ps[r] += __shfl_xor(ps[r], 4);
            ps[r] += __shfl_xor(ps[r], 8);
        }

        // ---- write h_t (hi/lo planes, M rows mrow..mrow+1) + partials ----
        #pragma unroll
        for (int r = 0; r < 2; ++r) {
            float hv = h_[r];
            uint u = __float_as_uint(hv);
            uint hb = u & 0xFFFF0000u;
            float lo = hv - __uint_as_float(hb);
            sHh[wb][mrow + r][n] = (u16)(u >> 16);
            sHl[wb][mrow + r][n] = (u16)f2bf(lo);
        }
        if (col == 0) {
            sPS[wb][rrow + 0][wg] = ps[0];
            sPS[wb][rrow + 1][wg] = ps[1];
        }

        __syncthreads();   // the ONLY barrier: h_t and partials visible

        #pragma unroll
        for (int r = 0; r < 2; ++r) {
            f4v tv = *(const f4v*)&sPS[wb][rrow + r][0];
            float tot = tv[0] + tv[1] + tv[2] + tv[3];
            float al = __expf(tanh_f(tot + fab));
            as[r] += al;
            ga[r] = fmaf(al, h_[r], ga[r]);
        }
    }

    // ---- epilogue: mu, beta per (row, d) ----
    const float pwa = Pw[n],  pwb = Pw[64 + n];
    const float fwa = Fbw[n], fwb = Fbw[64 + n];
    float pm[2], pv[2];
    #pragma unroll
    for (int r = 0; r < 2; ++r) {
        float gn = ga[r] * rcp_f(as[r]);
        pm[r] = fmaf(gn, pwa, h_[r] * pwb);
        pv[r] = fmaf(gn, fwa, h_[r] * fwb);
        pm[r] += __shfl_xor(pm[r], 1); pm[r] += __shfl_xor(pm[r], 2);
        pm[r] += __shfl_xor(pm[r], 4); pm[r] += __shfl_xor(pm[r], 8);
        pv[r] += __shfl_xor(pv[r], 1); pv[r] += __shfl_xor(pv[r], 2);
        pv[r] += __shfl_xor(pv[r], 4); pv[r] += __shfl_xor(pv[r], 8);
    }
    __syncthreads();   // in-loop sPS reads done
    if (col == 0) {
        #pragma unroll
        for (int r = 0; r < 2; ++r) {
            sPS[0][rrow + r][wg] = pm[r];
            sPV[rrow + r][wg]    = pv[r];
        }
    }
    __syncthreads();
    if (tid < R_TILE) {
        int r = tid;
        f4v a  = *(const f4v*)&sPS[0][r][0];
        f4v b2 = *(const f4v*)&sPV[r][0];
        float mu = a[0] + a[1] + a[2] + a[3] + Pb[0];
        float bt = __expf(tanh_f(b2[0] + b2[1] + b2[2] + b2[3] + Fbb[0]));
        wmu  [(r0 + r) * D_DIM + d] = mu;
        wbeta[(r0 + r) * D_DIM + d] = bt;
    }
}

// beta softmax over d + weighted sum -> out[b]
__global__ void imv_finalize(const float* __restrict__ wmu,
                             const float* __restrict__ wbeta,
                             float* __restrict__ out)
{
    int b = blockIdx.x * 64 + threadIdx.x;
    if (b >= B_ALL) return;
    float s1 = 0.f, s2 = 0.f;
    for (int d = 0; d < D_DIM; ++d) {
        float be = wbeta[b * D_DIM + d];
        s1 = fmaf(be, wmu[b * D_DIM + d], s1);
        s2 += be;
    }
    out[b] = s1 / s2;
}

extern "C" void kernel_launch(void* const* d_in, const int* in_sizes, int n_in,
                              void* d_out, int out_size, void* d_ws, size_t ws_size,
                              hipStream_t stream)
{
    const float* x   = (const float*)d_in[0];
    const float* U_j = (const float*)d_in[1];
    const float* U_i = (const float*)d_in[2];
    const float* U_f = (const float*)d_in[3];
    const float* U_o = (const float*)d_in[4];
    const float* W_j = (const float*)d_in[5];
    const float* W_i = (const float*)d_in[6];
    const float* W_f = (const float*)d_in[7];
    const float* W_o = (const float*)d_in[8];
    const float* b_j = (const float*)d_in[9];
    const float* b_i = (const float*)d_in[10];
    const float* b_f = (const float*)d_in[11];
    const float* b_o = (const float*)d_in[12];
    const float* Fan  = (const float*)d_in[13];
    const float* Fanb = (const float*)d_in[14];
    const float* Fbw  = (const float*)d_in[15];
    const float* Fbb  = (const float*)d_in[16];
    const float* Phw  = (const float*)d_in[17];
    const float* Phb  = (const float*)d_in[18];

    float* wmu   = (float*)d_ws;
    float* wbeta = wmu + B_ALL * D_DIM;

    imv_lstm_scan<<<dim3(512), dim3(256), 0, stream>>>(
        x, U_j, U_i, U_f, U_o, W_j, W_i, W_f, W_o,
        b_j, b_i, b_f, b_o, Fan, Fanb, Fbw, Fbb, Phw, Phb,
        wmu, wbeta);

    imv_finalize<<<dim3(2), dim3(64), 0, stream>>>(wmu, wbeta, (float*)d_out);
}

// Round 7
// 515.394 us; speedup vs baseline: 1.5089x; 1.1667x over previous
//
#include <hip/hip_runtime.h>

#define T_LEN 512
#define D_DIM 32
#define N_DIM 64
#define B_ALL 128
#define R_TILE 8      // real batch rows per block (M=16 MFMA, rows permuted)
#define M_DIM 16      // MFMA M dimension
#define HSTR 72       // ushort row stride for sHh/sHl: 16B-aligned, bank-spread

typedef short s8v __attribute__((ext_vector_type(8)));   // 8 bf16 (4 VGPRs)
typedef float f4v __attribute__((ext_vector_type(4)));   // MFMA C/D
typedef float f2v __attribute__((ext_vector_type(2)));
typedef unsigned int uint;
typedef unsigned short u16;

__device__ __forceinline__ float rcp_f(float x) {
#if __has_builtin(__builtin_amdgcn_rcpf)
    return __builtin_amdgcn_rcpf(x);
#else
    return 1.0f / x;
#endif
}
__device__ __forceinline__ float tanh_f(float x) {
    float e = __expf(2.0f * x);
    return 1.0f - 2.0f * rcp_f(e + 1.0f);
}
__device__ __forceinline__ float sig_f(float x) {
    return rcp_f(1.0f + __expf(-x));
}
__device__ __forceinline__ uint f2bf(float f) {   // fp32 -> bf16 bits, RNE
    uint u = __float_as_uint(f);
    return (u + 0x7FFFu + ((u >> 16) & 1u)) >> 16;
}
__device__ __forceinline__ s8v pack4(uint a, uint b, uint c, uint d_) {
    union { uint u[4]; s8v v; } x;
    x.u[0] = a; x.u[1] = b; x.u[2] = c; x.u[3] = d_;
    return x.v;
}

// R2 structure (best: 540us): grid 512 blocks (32 d x 16 row-octets) x
// 256 thr (4 waves) -> 2 independent blocks/CU, 2 de-phased waves/SIMD.
// R7 delta (one unit): ALPHA REDUCTION VIA MFMA. The A-fragments read at
// step t ARE h_{t-1} over all 64 n, so 4 extra MFMAs against a fan-vector
// B-fragment (B[k][col] = bf16(fan[k]) REPLICATED across all 16 cols) give
// every lane the full sum_n h_{t-1}[row,n]*fan[n] in C regs 0,1 (same rows
// as the gate acc). Deletes per wave-step: ps mul, the 8-shfl+8-add serial
// reduce (pre-barrier critical path), the sPS write, and the post-barrier
// b128 read + 4-term sum. No cross-lane ops remain in the alpha path.
// Alpha consumed one step deferred (reads old h_ regs before the gate
// update overwrites them; drained after the loop). Spurious t=-1 term
// (A-frags are exactly zero at t=0) cancelled exactly by as-init =
// -exp(tanh(fab)). Gate path is EXACT R2 (no C-fold: that rider put the
// sXT read on the MFMA-start path and cost +36us in R5/R6; no split-acc).
// NOTE: C-fold of x*U+b into MFMA C-in regressed (R5/R6) - keep acc=0.
__global__ void __launch_bounds__(256, 2)
imv_lstm_scan(const float* __restrict__ x,
              const float* __restrict__ Uj, const float* __restrict__ Ui,
              const float* __restrict__ Uf, const float* __restrict__ Uo,
              const float* __restrict__ Wj, const float* __restrict__ Wi,
              const float* __restrict__ Wf, const float* __restrict__ Wo,
              const float* __restrict__ bj, const float* __restrict__ bi_,
              const float* __restrict__ bf_, const float* __restrict__ bo,
              const float* __restrict__ Fa, const float* __restrict__ Fab,
              const float* __restrict__ Fbw, const float* __restrict__ Fbb,
              const float* __restrict__ Pw, const float* __restrict__ Pb,
              float* __restrict__ wmu, float* __restrict__ wbeta)
{
    __shared__ float sXT[T_LEN][R_TILE];     // 16 KB, [t][r]
    __shared__ u16   sHh[2][M_DIM][HSTR];    // 4.5 KB, h hi bf16, [buf][Mrow][k]
    __shared__ u16   sHl[2][M_DIM][HSTR];    // 4.5 KB, h lo bf16
    __shared__ float sPS[R_TILE][4];         // epilogue mu partials
    __shared__ float sPV[R_TILE][4];         // epilogue beta partials

    const int tid  = threadIdx.x;
    const int lane = tid & 63;
    const int wg   = tid >> 6;               // 0..3 (n-group)
    const int quad = lane >> 4;              // 0..3
    const int col  = lane & 15;
    const int d    = blockIdx.x & 31;
    const int rt   = blockIdx.x >> 5;        // 0..15
    const int r0   = rt * R_TILE;
    const int n    = wg * 16 + col;          // this lane's n
    const int mrow = quad * 4;               // first M row of lane's 2 rows
    const int rrow = quad * 2;               // first real row of lane's 2

    // ---- stage x transposed: sXT[t][r] ----
    for (int i = tid; i < R_TILE * T_LEN; i += 256) {
        int t = i >> 3, r = i & 7;
        sXT[t][r] = x[((size_t)(r0 + r) * T_LEN + t) * D_DIM + d];
    }
    // ---- h0 = 0 (zero both buffers; unwritten M rows stay 0 forever) ----
    for (int i = tid; i < 2 * M_DIM * HSTR; i += 256) {
        ((u16*)sHh)[i] = 0; ((u16*)sHl)[i] = 0;
    }

    // ---- W fragments into registers: Bh/Bl[gate][k-chunk] ----
    s8v Bh[4][2], Bl[4][2];
    #pragma unroll
    for (int g = 0; g < 4; ++g) {
        const float* Wg = (g == 0 ? Wj : g == 1 ? Wi : g == 2 ? Wf : Wo)
                          + d * (N_DIM * N_DIM);
        #pragma unroll
        for (int c = 0; c < 2; ++c) {
            uint hp[4], lp[4];
            #pragma unroll
            for (int jp = 0; jp < 4; ++jp) {
                float w0 = Wg[(32 * c + quad * 8 + 2 * jp + 0) * N_DIM + n];
                float w1 = Wg[(32 * c + quad * 8 + 2 * jp + 1) * N_DIM + n];
                uint u0 = __float_as_uint(w0), u1 = __float_as_uint(w1);
                uint h0b = u0 & 0xFFFF0000u, h1b = u1 & 0xFFFF0000u;
                float l0 = w0 - __uint_as_float(h0b);
                float l1 = w1 - __uint_as_float(h1b);
                hp[jp] = (u0 >> 16) | h1b;
                lp[jp] = f2bf(l0) | (f2bf(l1) << 16);
            }
            Bh[g][c] = pack4(hp[0], hp[1], hp[2], hp[3]);
            Bl[g][c] = pack4(lp[0], lp[1], lp[2], lp[3]);
        }
    }

    // ---- fan-vector B fragment: B[k][col] = bf16(fan[k]), SAME for every
    //      col -> D[row][col] = sum_k h[row,k]*fan[k] lands in ALL lanes ----
    s8v Ff[2];
    #pragma unroll
    for (int c = 0; c < 2; ++c) {
        uint p[4];
        #pragma unroll
        for (int jp = 0; jp < 4; ++jp) {
            float f0 = Fa[d * N_DIM + 32 * c + quad * 8 + 2 * jp + 0];
            float f1 = Fa[d * N_DIM + 32 * c + quad * 8 + 2 * jp + 1];
            p[jp] = f2bf(f0) | (f2bf(f1) << 16);
        }
        Ff[c] = pack4(p[0], p[1], p[2], p[3]);
    }

    const int dn = d * N_DIM + n;
    const float u_j = Uj[dn], u_i = Ui[dn], u_f = Uf[dn], u_o = Uo[dn];
    const float cbj = bj[dn], cbi = bi_[dn], cbf = bf_[dn], cbo = bo[dn];
    const float fab = Fab[d];

    __syncthreads();

    float c_[2] = {0.f, 0.f};
    float h_[2] = {0.f, 0.f};
    float ga[2] = {0.f, 0.f};
    // as init cancels the spurious t=-1 alpha term exactly: at t=0 the
    // A-frags are exactly 0 -> af=0 -> al = exp(tanh(fab)).
    const float al_m1 = __expf(tanh_f(fab));
    float as[2] = {-al_m1, -al_m1};

    #pragma unroll 2
    for (int t = 0; t < T_LEN; ++t) {
        const int wb = t & 1;        // write buffer (h_t)
        const int rb = wb ^ 1;       // read buffer (h_{t-1})

        // ---- A fragments: direct b128 reads, zero unpack ----
        s8v Ah[2], Al[2];
        #pragma unroll
        for (int c = 0; c < 2; ++c) {
            Ah[c] = *(const s8v*)&sHh[rb][col][32 * c + quad * 8];
            Al[c] = *(const s8v*)&sHl[rb][col][32 * c + quad * 8];
        }

        // ---- alpha logit for step t-1 via MFMA (2 independent 2-chains) ----
        f4v af0 = {0.f, 0.f, 0.f, 0.f};
        f4v af1 = {0.f, 0.f, 0.f, 0.f};
        af0 = __builtin_amdgcn_mfma_f32_16x16x32_bf16(Ah[0], Ff[0], af0, 0, 0, 0);
        af0 = __builtin_amdgcn_mfma_f32_16x16x32_bf16(Al[0], Ff[0], af0, 0, 0, 0);
        af1 = __builtin_amdgcn_mfma_f32_16x16x32_bf16(Ah[1], Ff[1], af1, 0, 0, 0);
        af1 = __builtin_amdgcn_mfma_f32_16x16x32_bf16(Al[1], Ff[1], af1, 0, 0, 0);

        // ---- 24 gate MFMAs: exact R2 (single acc chain, zero C-in) ----
        f4v acc[4];
        #pragma unroll
        for (int g = 0; g < 4; ++g) {
            f4v a = {0.f, 0.f, 0.f, 0.f};
            #pragma unroll
            for (int c = 0; c < 2; ++c) {
                a = __builtin_amdgcn_mfma_f32_16x16x32_bf16(Ah[c], Bh[g][c], a, 0, 0, 0);
                a = __builtin_amdgcn_mfma_f32_16x16x32_bf16(Al[c], Bh[g][c], a, 0, 0, 0);
                a = __builtin_amdgcn_mfma_f32_16x16x32_bf16(Ah[c], Bl[g][c], a, 0, 0, 0);
            }
            acc[g] = a;
        }

        // ---- alpha(t-1): independent of the gate chain, uses OLD h_ ----
        #pragma unroll
        for (int r = 0; r < 2; ++r) {
            float tot = af0[r] + af1[r] + fab;
            float al = __expf(tanh_f(tot));
            as[r] += al;
            ga[r] = fmaf(al, h_[r], ga[r]);
        }

        // ---- stage 3: C regs 0,1 = real rows rrow, rrow+1 at n ----
        f2v xr = *(const f2v*)&sXT[t][rrow];
        #pragma unroll
        for (int r = 0; r < 2; ++r) {
            float xv = xr[r];
            float jp = acc[0][r] + fmaf(xv, u_j, cbj);
            float ip = acc[1][r] + fmaf(xv, u_i, cbi);
            float fp = acc[2][r] + fmaf(xv, u_f, cbf);
            float op = acc[3][r] + fmaf(xv, u_o, cbo);
            c_[r] = fmaf(c_[r], sig_f(fp), sig_f(ip) * tanh_f(jp));
            h_[r] = sig_f(op) * tanh_f(c_[r]);
        }

        // ---- write h_t (hi/lo planes, M rows mrow..mrow+1) ----
        #pragma unroll
        for (int r = 0; r < 2; ++r) {
            float hv = h_[r];
            uint u = __float_as_uint(hv);
            uint hb = u & 0xFFFF0000u;
            float lo = hv - __uint_as_float(hb);
            sHh[wb][mrow + r][n] = (u16)(u >> 16);
            sHl[wb][mrow + r][n] = (u16)f2bf(lo);
        }

        __syncthreads();   // the ONLY barrier: h_t planes visible
    }

    // ---- drain alpha(T-1): h_{T-1} is in buffer (T-1)&1 = 1 ----
    {
        s8v Ah[2], Al[2];
        #pragma unroll
        for (int c = 0; c < 2; ++c) {
            Ah[c] = *(const s8v*)&sHh[1][col][32 * c + quad * 8];
            Al[c] = *(const s8v*)&sHl[1][col][32 * c + quad * 8];
        }
        f4v af0 = {0.f, 0.f, 0.f, 0.f};
        f4v af1 = {0.f, 0.f, 0.f, 0.f};
        af0 = __builtin_amdgcn_mfma_f32_16x16x32_bf16(Ah[0], Ff[0], af0, 0, 0, 0);
        af0 = __builtin_amdgcn_mfma_f32_16x16x32_bf16(Al[0], Ff[0], af0, 0, 0, 0);
        af1 = __builtin_amdgcn_mfma_f32_16x16x32_bf16(Ah[1], Ff[1], af1, 0, 0, 0);
        af1 = __builtin_amdgcn_mfma_f32_16x16x32_bf16(Al[1], Ff[1], af1, 0, 0, 0);
        #pragma unroll
        for (int r = 0; r < 2; ++r) {
            float tot = af0[r] + af1[r] + fab;
            float al = __expf(tanh_f(tot));
            as[r] += al;
            ga[r] = fmaf(al, h_[r], ga[r]);
        }
    }

    // ---- epilogue: mu, beta per (row, d) ----
    const float pwa = Pw[n],  pwb = Pw[64 + n];
    const float fwa = Fbw[n], fwb = Fbw[64 + n];
    float pm[2], pv[2];
    #pragma unroll
    for (int r = 0; r < 2; ++r) {
        float gn = ga[r] * rcp_f(as[r]);
        pm[r] = fmaf(gn, pwa, h_[r] * pwb);
        pv[r] = fmaf(gn, fwa, h_[r] * fwb);
        pm[r] += __shfl_xor(pm[r], 1); pm[r] += __shfl_xor(pm[r], 2);
        pm[r] += __shfl_xor(pm[r], 4); pm[r] += __shfl_xor(pm[r], 8);
        pv[r] += __shfl_xor(pv[r], 1); pv[r] += __shfl_xor(pv[r], 2);
        pv[r] += __shfl_xor(pv[r], 4); pv[r] += __shfl_xor(pv[r], 8);
    }
    if (col == 0) {
        #pragma unroll
        for (int r = 0; r < 2; ++r) {
            sPS[rrow + r][wg] = pm[r];
            sPV[rrow + r][wg] = pv[r];
        }
    }
    __syncthreads();
    if (tid < R_TILE) {
        int r = tid;
        f4v a  = *(const f4v*)&sPS[r][0];
        f4v b2 = *(const f4v*)&sPV[r][0];
        float mu = a[0] + a[1] + a[2] + a[3] + Pb[0];
        float bt = __expf(tanh_f(b2[0] + b2[1] + b2[2] + b2[3] + Fbb[0]));
        wmu  [(r0 + r) * D_DIM + d] = mu;
        wbeta[(r0 + r) * D_DIM + d] = bt;
    }
}

// beta softmax over d + weighted sum -> out[b]
__global__ void imv_finalize(const float* __restrict__ wmu,
                             const float* __restrict__ wbeta,
                             float* __restrict__ out)
{
    int b = blockIdx.x * 64 + threadIdx.x;
    if (b >= B_ALL) return;
    float s1 = 0.f, s2 = 0.f;
    for (int d = 0; d < D_DIM; ++d) {
        float be = wbeta[b * D_DIM + d];
        s1 = fmaf(be, wmu[b * D_DIM + d], s1);
        s2 += be;
    }
    out[b] = s1 / s2;
}

extern "C" void kernel_launch(void* const* d_in, const int* in_sizes, int n_in,
                              void* d_out, int out_size, void* d_ws, size_t ws_size,
                              hipStream_t stream)
{
    const float* x   = (const float*)d_in[0];
    const float* U_j = (const float*)d_in[1];
    const float* U_i = (const float*)d_in[2];
    const float* U_f = (const float*)d_in[3];
    const float* U_o = (const float*)d_in[4];
    const float* W_j = (const float*)d_in[5];
    const float* W_i = (const float*)d_in[6];
    const float* W_f = (const float*)d_in[7];
    const float* W_o = (const float*)d_in[8];
    const float* b_j = (const float*)d_in[9];
    const float* b_i = (const float*)d_in[10];
    const float* b_f = (const float*)d_in[11];
    const float* b_o = (const float*)d_in[12];
    const float* Fan  = (const float*)d_in[13];
    const float* Fanb = (const float*)d_in[14];
    const float* Fbw  = (const float*)d_in[15];
    const float* Fbb  = (const float*)d_in[16];
    const float* Phw  = (const float*)d_in[17];
    const float* Phb  = (const float*)d_in[18];

    float* wmu   = (float*)d_ws;
    float* wbeta = wmu + B_ALL * D_DIM;

    imv_lstm_scan<<<dim3(512), dim3(256), 0, stream>>>(
        x, U_j, U_i, U_f, U_o, W_j, W_i, W_f, W_o,
        b_j, b_i, b_f, b_o, Fan, Fanb, Fbw, Fbb, Phw, Phb,
        wmu, wbeta);

    imv_finalize<<<dim3(2), dim3(64), 0, stream>>>(wmu, wbeta, (float*)d_out);
}